// Round 6
// baseline (507.649 us; speedup 1.0000x reference)
//
#include <hip/hip_runtime.h>

// GCN 3-layer forward on gfx950.
// Round 6: GEMM restructured for occupancy + store coalescing.
//  - 16 rows/wave (2x wave count; grid-limit ceiling 38%->76%)
//  - epilogue stages C tile in padded LDS (hi pass, lo pass) -> 8B dwordx2
//    stores instead of 2B scalar stores
//  - convw folded into fill_k launch

#define IN_CH 128

typedef __attribute__((ext_vector_type(8))) short bf16x8;
typedef __attribute__((ext_vector_type(4))) float f32x4;

__device__ inline unsigned short f2bf_rne(float f) {
    unsigned u = __float_as_uint(f);
    unsigned r = (u + 0x7FFFu + ((u >> 16) & 1u)) >> 16;
    return (unsigned short)r;
}
__device__ inline float bf2f(unsigned short h) {
    return __uint_as_float(((unsigned)h) << 16);
}
__device__ inline float bf2f_lo(unsigned m) {
    return __uint_as_float(m << 16);
}
__device__ inline float bf2f_hi(unsigned m) {
    return __uint_as_float(m & 0xffff0000u);
}

// ---------------- degree count ----------------
__global__ __launch_bounds__(256) void cnt_k(const int* __restrict__ dst,
                                             int* __restrict__ cnt, int E) {
    int e = blockIdx.x * 256 + threadIdx.x;
    if (e < E) atomicAdd(&cnt[dst[e]], 1);
}

// ---------------- scan stage 1 (+ dinv fused) ----------------
__global__ __launch_bounds__(256) void scan1_k(const int* __restrict__ cnt,
                                               int* __restrict__ bsum,
                                               float* __restrict__ dinv, int N) {
    __shared__ int s[256];
    int tid = threadIdx.x;
    int i = blockIdx.x * 256 + tid;
    int v = (i < N) ? cnt[i] : 0;
    if (i < N) dinv[i] = rsqrtf((float)v + 1.0f);
    s[tid] = v;
    __syncthreads();
    for (int off = 128; off > 0; off >>= 1) {
        if (tid < off) s[tid] += s[tid + off];
        __syncthreads();
    }
    if (tid == 0) bsum[blockIdx.x] = s[0];
}

__global__ __launch_bounds__(512) void scan2_k(int* __restrict__ bsum, int nb) {
    __shared__ int s[512];
    __shared__ int carry_s;
    int tid = threadIdx.x;
    if (tid == 0) carry_s = 0;
    __syncthreads();
    for (int base = 0; base < nb; base += 512) {
        int c = carry_s;
        int i = base + tid;
        int v = (i < nb) ? bsum[i] : 0;
        s[tid] = v;
        __syncthreads();
        for (int off = 1; off < 512; off <<= 1) {
            int t = (tid >= off) ? s[tid - off] : 0;
            __syncthreads();
            s[tid] += t;
            __syncthreads();
        }
        if (i < nb) bsum[i] = s[tid] - v + c;
        __syncthreads();
        if (tid == 0) carry_s = c + s[511];
        __syncthreads();
    }
}

__global__ __launch_bounds__(256) void scan3_k(const int* __restrict__ cnt,
                                               const int* __restrict__ bsum,
                                               int* __restrict__ rowptr, int N) {
    __shared__ int s[256];
    int tid = threadIdx.x;
    int i = blockIdx.x * 256 + tid;
    int v = (i < N) ? cnt[i] : 0;
    s[tid] = v;
    __syncthreads();
    for (int off = 1; off < 256; off <<= 1) {
        int t = (tid >= off) ? s[tid - off] : 0;
        __syncthreads();
        s[tid] += t;
        __syncthreads();
    }
    if (i < N) rowptr[i] = s[tid] - v + bsum[blockIdx.x];
}

// ---------------- fill (CSR pairs) + weight conversion, one launch ----------
__device__ inline void convw_one(const float* W, unsigned short* hi,
                                 unsigned short* lo, int FOUT, int id) {
    int n = id >> 7, k = id & 127;
    float v = W[k * FOUT + n];
    unsigned short h = f2bf_rne(v);
    hi[id] = h;
    lo[id] = f2bf_rne(v - bf2f(h));
}

__global__ __launch_bounds__(256) void fill_conv_k(
    const int* __restrict__ src, const int* __restrict__ dst,
    const float* __restrict__ dinv, int* __restrict__ rowptr,
    int2* __restrict__ pairs, int E, int fillBlocks,
    const float* __restrict__ W1, const float* __restrict__ W2,
    const float* __restrict__ W3,
    unsigned short* __restrict__ W1h, unsigned short* __restrict__ W1l,
    unsigned short* __restrict__ W2h, unsigned short* __restrict__ W2l,
    unsigned short* __restrict__ W3h, unsigned short* __restrict__ W3l) {
    if ((int)blockIdx.x < fillBlocks) {
        int e = blockIdx.x * 256 + threadIdx.x;
        if (e < E) {
            int s = src[e], d = dst[e];
            float nrm = dinv[s] * dinv[d];
            int pos = atomicAdd(&rowptr[d], 1);
            pairs[pos] = make_int2(s, __float_as_int(nrm));
        }
    } else {
        int id = (blockIdx.x - fillBlocks) * 256 + threadIdx.x;
        if (id < 16384) convw_one(W1, W1h, W1l, 128, id);
        else if (id < 32768) convw_one(W2, W2h, W2l, 128, id - 16384);
        else if (id < 40960) convw_one(W3, W3h, W3l, 64, id - 32768);
    }
}

// ---------------- MFMA GEMM: T[N][FOUT] = A[N][128] @ W[128][FOUT] ----------
// Split-precision bf16: C = AhBh + AlBh + AhBl (fp32 acc). Output bf16 hi/lo.
// Wave = 16 rows x FOUT cols. Block = 4 waves = 64 rows. 16x16x32 layouts
// (m89): A[m=lane&15][k=quad*8+j], B = Wt[n=lane&15][k], C: col=lane&15,
// row=quad*4+reg. Epilogue: stage u16 tile in LDS (stride 132 -> 2-way bank
// alias only), re-read as contiguous 8B runs per lane, dwordx2 stores.
__device__ inline void split8(const float* __restrict__ p, bf16x8& hi, bf16x8& lo) {
    float4 v0 = *(const float4*)p;
    float4 v1 = *(const float4*)(p + 4);
    float vv[8] = {v0.x, v0.y, v0.z, v0.w, v1.x, v1.y, v1.z, v1.w};
#pragma unroll
    for (int i = 0; i < 8; ++i) {
        unsigned short h = f2bf_rne(vv[i]);
        hi[i] = (short)h;
        lo[i] = (short)f2bf_rne(vv[i] - bf2f(h));
    }
}

template <int FOUT, bool AF32>
__global__ __launch_bounds__(256) void mfma_gemm(const float* __restrict__ Af,
                                                 const unsigned short* __restrict__ Ahi,
                                                 const unsigned short* __restrict__ Alo,
                                                 const unsigned short* __restrict__ Bhi,
                                                 const unsigned short* __restrict__ Blo,
                                                 unsigned short* __restrict__ Thi,
                                                 unsigned short* __restrict__ Tlo,
                                                 int N) {
    constexpr int NCT = FOUT / 16;
    const int tid = threadIdx.x;
    const int wv = tid >> 6, lane = tid & 63;
    const int quad = lane >> 4, l16 = lane & 15;
    const int row0 = blockIdx.x * 64 + wv * 16;  // 16 rows per wave

    f32x4 acc[NCT];
#pragma unroll
    for (int ct = 0; ct < NCT; ++ct)
        acc[ct] = (f32x4){0.f, 0.f, 0.f, 0.f};

    const int ra = AF32 ? min(row0 + l16, N - 1) : (row0 + l16);

#pragma unroll
    for (int ks = 0; ks < 4; ++ks) {
        const int ko = ks * 32 + quad * 8;
        bf16x8 ah, al;
        if (AF32) {
            split8(Af + (size_t)ra * 128 + ko, ah, al);
        } else {
            ah = *(const bf16x8*)(Ahi + (size_t)ra * 128 + ko);
            al = *(const bf16x8*)(Alo + (size_t)ra * 128 + ko);
        }
#pragma unroll
        for (int ct = 0; ct < NCT; ++ct) {
            bf16x8 bh = *(const bf16x8*)(Bhi + (size_t)(ct * 16 + l16) * 128 + ko);
            bf16x8 bl = *(const bf16x8*)(Blo + (size_t)(ct * 16 + l16) * 128 + ko);
            acc[ct] = __builtin_amdgcn_mfma_f32_16x16x32_bf16(ah, bh, acc[ct], 0, 0, 0);
            acc[ct] = __builtin_amdgcn_mfma_f32_16x16x32_bf16(al, bh, acc[ct], 0, 0, 0);
            acc[ct] = __builtin_amdgcn_mfma_f32_16x16x32_bf16(ah, bl, acc[ct], 0, 0, 0);
        }
    }

    // ---- coalesced epilogue via LDS: hi pass, then lo pass ----
    __shared__ unsigned short stg[4][16][132];  // stride 132: write banks spread
    const int tr = lane >> 2;                    // row within wave tile (0..15)
    const int c0 = (lane & 3) * (FOUT / 4);      // col start for this lane
    const int grow = row0 + tr;
    const bool wr = grow < N;

    // pass 0: hi
#pragma unroll
    for (int ct = 0; ct < NCT; ++ct)
#pragma unroll
        for (int r = 0; r < 4; ++r)
            stg[wv][quad * 4 + r][ct * 16 + l16] = f2bf_rne(acc[ct][r]);
    __syncthreads();
    if (wr) {
        const uint2* sp = (const uint2*)&stg[wv][tr][c0];
        uint2* dp = (uint2*)(Thi + (size_t)grow * FOUT + c0);
#pragma unroll
        for (int i = 0; i < FOUT / 16; ++i) dp[i] = sp[i];
    }
    __syncthreads();
    // pass 1: lo
#pragma unroll
    for (int ct = 0; ct < NCT; ++ct)
#pragma unroll
        for (int r = 0; r < 4; ++r) {
            float v = acc[ct][r];
            unsigned short h = f2bf_rne(v);
            stg[wv][quad * 4 + r][ct * 16 + l16] = f2bf_rne(v - bf2f(h));
        }
    __syncthreads();
    if (wr) {
        const uint2* sp = (const uint2*)&stg[wv][tr][c0];
        uint2* dp = (uint2*)(Tlo + (size_t)grow * FOUT + c0);
#pragma unroll
        for (int i = 0; i < FOUT / 16; ++i) dp[i] = sp[i];
    }
}

// ---------------- aggregation: wave per row, no atomics, no shfl ----------
// res[row] = b + (Thi+Tlo)[row]*dinv^2 + sum_e norm_e * Thi[src_e]
template <int FOUT, bool SPLIT>
__global__ __launch_bounds__(256) void gather_k(const int* __restrict__ rowend,
                                                const int2* __restrict__ pairs,
                                                const float* __restrict__ dinv,
                                                const unsigned short* __restrict__ Thi,
                                                const unsigned short* __restrict__ Tlo,
                                                const float* __restrict__ bias,
                                                float* __restrict__ out,
                                                unsigned short* __restrict__ outHi,
                                                unsigned short* __restrict__ outLo,
                                                int N) {
    const int wave = threadIdx.x >> 6;
    const int lane = threadIdx.x & 63;
    const int row = blockIdx.x * 4 + wave;
    if (row >= N) return;

    const int start = (row == 0) ? 0 : rowend[row - 1];
    const int end = rowend[row];
    const float dr = dinv[row];

    if (FOUT == 128) {
        const unsigned* thi32 = (const unsigned*)Thi;  // bf16x2 per dword
        const unsigned* tlo32 = (const unsigned*)Tlo;
        unsigned sh = thi32[(size_t)row * 64 + lane];
        unsigned sl = tlo32[(size_t)row * 64 + lane];
        float2 bb = *(const float2*)(bias + lane * 2);
        float ax = bb.x + (bf2f_lo(sh) + bf2f_lo(sl)) * dr * dr;
        float ay = bb.y + (bf2f_hi(sh) + bf2f_hi(sl)) * dr * dr;

        int j = start;
        if ((j & 1) && j < end) {
            int2 pv = pairs[j];
            unsigned m = thi32[(size_t)pv.x * 64 + lane];
            float n = __int_as_float(pv.y);
            ax += n * bf2f_lo(m);
            ay += n * bf2f_hi(m);
            ++j;
        }
        for (; j + 4 <= end; j += 4) {
            int4 p01 = *(const int4*)(pairs + j);
            int4 p23 = *(const int4*)(pairs + j + 2);
            unsigned m0 = thi32[(size_t)p01.x * 64 + lane];
            unsigned m1 = thi32[(size_t)p01.z * 64 + lane];
            unsigned m2 = thi32[(size_t)p23.x * 64 + lane];
            unsigned m3 = thi32[(size_t)p23.z * 64 + lane];
            float n0 = __int_as_float(p01.y), n1 = __int_as_float(p01.w);
            float n2 = __int_as_float(p23.y), n3 = __int_as_float(p23.w);
            ax += n0 * bf2f_lo(m0); ay += n0 * bf2f_hi(m0);
            ax += n1 * bf2f_lo(m1); ay += n1 * bf2f_hi(m1);
            ax += n2 * bf2f_lo(m2); ay += n2 * bf2f_hi(m2);
            ax += n3 * bf2f_lo(m3); ay += n3 * bf2f_hi(m3);
        }
        for (; j < end; ++j) {
            int2 pv = pairs[j];
            unsigned m = thi32[(size_t)pv.x * 64 + lane];
            float n = __int_as_float(pv.y);
            ax += n * bf2f_lo(m);
            ay += n * bf2f_hi(m);
        }

        if (SPLIT) {
            float vx = fmaxf(ax, 0.f), vy = fmaxf(ay, 0.f);
            ushort2 h, l;
            h.x = f2bf_rne(vx); l.x = f2bf_rne(vx - bf2f(h.x));
            h.y = f2bf_rne(vy); l.y = f2bf_rne(vy - bf2f(h.y));
            *(ushort2*)(outHi + (size_t)row * 128 + lane * 2) = h;
            *(ushort2*)(outLo + (size_t)row * 128 + lane * 2) = l;
        } else {
            float2 o; o.x = ax; o.y = ay;
            *(float2*)(out + (size_t)row * 128 + lane * 2) = o;
        }
    } else {
        float self = bf2f(Thi[(size_t)row * FOUT + lane]) + bf2f(Tlo[(size_t)row * FOUT + lane]);
        float acc = bias[lane] + self * dr * dr;

        int j = start;
        if ((j & 1) && j < end) {
            int2 pv = pairs[j];
            acc += __int_as_float(pv.y) * bf2f(Thi[(size_t)pv.x * FOUT + lane]);
            ++j;
        }
        for (; j + 4 <= end; j += 4) {
            int4 p01 = *(const int4*)(pairs + j);
            int4 p23 = *(const int4*)(pairs + j + 2);
            float m0 = bf2f(Thi[(size_t)p01.x * FOUT + lane]);
            float m1 = bf2f(Thi[(size_t)p01.z * FOUT + lane]);
            float m2 = bf2f(Thi[(size_t)p23.x * FOUT + lane]);
            float m3 = bf2f(Thi[(size_t)p23.z * FOUT + lane]);
            acc += __int_as_float(p01.y) * m0 + __int_as_float(p01.w) * m1 +
                   __int_as_float(p23.y) * m2 + __int_as_float(p23.w) * m3;
        }
        for (; j < end; ++j) {
            int2 pv = pairs[j];
            acc += __int_as_float(pv.y) * bf2f(Thi[(size_t)pv.x * FOUT + lane]);
        }
        out[(size_t)row * FOUT + lane] = acc;
    }
}

extern "C" void kernel_launch(void* const* d_in, const int* in_sizes, int n_in,
                              void* d_out, int out_size, void* d_ws, size_t ws_size,
                              hipStream_t stream) {
    const float* x  = (const float*)d_in[0];
    const int* eidx = (const int*)d_in[1];
    const float* W1 = (const float*)d_in[2];
    const float* b1 = (const float*)d_in[3];
    const float* W2 = (const float*)d_in[4];
    const float* b2 = (const float*)d_in[5];
    const float* W3 = (const float*)d_in[6];
    const float* b3 = (const float*)d_in[7];
    float* out = (float*)d_out;

    const int N = in_sizes[0] / IN_CH;
    const int E = in_sizes[1] / 2;
    const int* src = eidx;
    const int* dst = eidx + E;
    const int Npad = ((N + 127) / 128) * 128;  // buffer row allocation
    const int nb = (N + 255) / 256;

    auto align = [](size_t v) { return (v + 255) / 256 * 256; };
    char* p = (char*)d_ws;
    int* cnt = (int*)p;            p += align((size_t)N * 4);
    int* rowptr = (int*)p;         p += align((size_t)N * 4);
    int* bsum = (int*)p;           p += align((size_t)nb * 4);
    float* dinv = (float*)p;       p += align((size_t)N * 4);
    int2* pairs = (int2*)p;        p += align((size_t)E * 8);
    unsigned short* Ahi = (unsigned short*)p;  p += align((size_t)Npad * 128 * 2);
    unsigned short* Alo = (unsigned short*)p;  p += align((size_t)Npad * 128 * 2);
    unsigned short* Thi = (unsigned short*)p;  p += align((size_t)Npad * 128 * 2);
    unsigned short* Tlo = (unsigned short*)p;  p += align((size_t)Npad * 128 * 2);
    unsigned short* W1h = (unsigned short*)p;  p += align(128 * 128 * 2);
    unsigned short* W1l = (unsigned short*)p;  p += align(128 * 128 * 2);
    unsigned short* W2h = (unsigned short*)p;  p += align(128 * 128 * 2);
    unsigned short* W2l = (unsigned short*)p;  p += align(128 * 128 * 2);
    unsigned short* W3h = (unsigned short*)p;  p += align(64 * 128 * 2);
    unsigned short* W3l = (unsigned short*)p;

    // ---- CSR build (once; reused by all 3 layers) ----
    hipMemsetAsync(cnt, 0, (size_t)N * 4, stream);
    cnt_k<<<(E + 255) / 256, 256, 0, stream>>>(dst, cnt, E);
    scan1_k<<<nb, 256, 0, stream>>>(cnt, bsum, dinv, N);
    scan2_k<<<1, 512, 0, stream>>>(bsum, nb);
    scan3_k<<<nb, 256, 0, stream>>>(cnt, bsum, rowptr, N);
    const int fillBlocks = (E + 255) / 256;
    fill_conv_k<<<fillBlocks + 160, 256, 0, stream>>>(src, dst, dinv, rowptr, pairs,
                                                      E, fillBlocks, W1, W2, W3,
                                                      W1h, W1l, W2h, W2l, W3h, W3l);
    // rowptr[i] now holds END of row i.

    const int gemm_blocks = (N + 63) / 64;  // 64 rows per block
    const int gather_blocks = (N + 3) / 4;

    // Layer 1 (A = x fp32, split in-register)
    mfma_gemm<128, true><<<gemm_blocks, 256, 0, stream>>>(x, nullptr, nullptr,
                                                          W1h, W1l, Thi, Tlo, N);
    gather_k<128, true><<<gather_blocks, 256, 0, stream>>>(rowptr, pairs, dinv, Thi, Tlo,
                                                           b1, nullptr, Ahi, Alo, N);
    // Layer 2
    mfma_gemm<128, false><<<gemm_blocks, 256, 0, stream>>>(nullptr, Ahi, Alo,
                                                           W2h, W2l, Thi, Tlo, N);
    gather_k<128, true><<<gather_blocks, 256, 0, stream>>>(rowptr, pairs, dinv, Thi, Tlo,
                                                           b2, nullptr, Ahi, Alo, N);
    // Layer 3
    mfma_gemm<64, false><<<gemm_blocks, 256, 0, stream>>>(nullptr, Ahi, Alo,
                                                          W3h, W3l, Thi, Tlo, N);
    gather_k<64, false><<<gather_blocks, 256, 0, stream>>>(rowptr, pairs, dinv, Thi, Tlo,
                                                           b3, out, nullptr, nullptr, N);
}

// Round 7
// 426.192 us; speedup vs baseline: 1.1911x; 1.1911x over previous
//
#include <hip/hip_runtime.h>

// GCN 3-layer forward on gfx950.
// Round 7: revert GEMM to R5 structure (32 rows/wave, direct stores — R6's
// 16-row + LDS epilogue regressed: B-load traffic per MFMA doubled and VGPR
// fell to 52). New: drop the Ah*Bl term (B-residual, rel ~2^-9) -> 2 MFMA
// passes sharing one B fragment: B loads (the stall source) halve, MFMA -33%,
// Wl buffers gone. C = (Ah+Al)*Bh, fp32 acc.

#define IN_CH 128

typedef __attribute__((ext_vector_type(8))) short bf16x8;
typedef __attribute__((ext_vector_type(4))) float f32x4;

__device__ inline unsigned short f2bf_rne(float f) {
    unsigned u = __float_as_uint(f);
    unsigned r = (u + 0x7FFFu + ((u >> 16) & 1u)) >> 16;
    return (unsigned short)r;
}
__device__ inline float bf2f(unsigned short h) {
    return __uint_as_float(((unsigned)h) << 16);
}
__device__ inline float bf2f_lo(unsigned m) {
    return __uint_as_float(m << 16);
}
__device__ inline float bf2f_hi(unsigned m) {
    return __uint_as_float(m & 0xffff0000u);
}

// ---------------- degree count ----------------
__global__ __launch_bounds__(256) void cnt_k(const int* __restrict__ dst,
                                             int* __restrict__ cnt, int E) {
    int e = blockIdx.x * 256 + threadIdx.x;
    if (e < E) atomicAdd(&cnt[dst[e]], 1);
}

// ---------------- scan stage 1 (+ dinv fused) ----------------
__global__ __launch_bounds__(256) void scan1_k(const int* __restrict__ cnt,
                                               int* __restrict__ bsum,
                                               float* __restrict__ dinv, int N) {
    __shared__ int s[256];
    int tid = threadIdx.x;
    int i = blockIdx.x * 256 + tid;
    int v = (i < N) ? cnt[i] : 0;
    if (i < N) dinv[i] = rsqrtf((float)v + 1.0f);
    s[tid] = v;
    __syncthreads();
    for (int off = 128; off > 0; off >>= 1) {
        if (tid < off) s[tid] += s[tid + off];
        __syncthreads();
    }
    if (tid == 0) bsum[blockIdx.x] = s[0];
}

__global__ __launch_bounds__(512) void scan2_k(int* __restrict__ bsum, int nb) {
    __shared__ int s[512];
    __shared__ int carry_s;
    int tid = threadIdx.x;
    if (tid == 0) carry_s = 0;
    __syncthreads();
    for (int base = 0; base < nb; base += 512) {
        int c = carry_s;
        int i = base + tid;
        int v = (i < nb) ? bsum[i] : 0;
        s[tid] = v;
        __syncthreads();
        for (int off = 1; off < 512; off <<= 1) {
            int t = (tid >= off) ? s[tid - off] : 0;
            __syncthreads();
            s[tid] += t;
            __syncthreads();
        }
        if (i < nb) bsum[i] = s[tid] - v + c;
        __syncthreads();
        if (tid == 0) carry_s = c + s[511];
        __syncthreads();
    }
}

__global__ __launch_bounds__(256) void scan3_k(const int* __restrict__ cnt,
                                               const int* __restrict__ bsum,
                                               int* __restrict__ rowptr, int N) {
    __shared__ int s[256];
    int tid = threadIdx.x;
    int i = blockIdx.x * 256 + tid;
    int v = (i < N) ? cnt[i] : 0;
    s[tid] = v;
    __syncthreads();
    for (int off = 1; off < 256; off <<= 1) {
        int t = (tid >= off) ? s[tid - off] : 0;
        __syncthreads();
        s[tid] += t;
        __syncthreads();
    }
    if (i < N) rowptr[i] = s[tid] - v + bsum[blockIdx.x];
}

// ---------------- fill (CSR pairs) + weight conversion, one launch ----------
__device__ inline void convw_one(const float* W, unsigned short* hi, int FOUT, int id) {
    int n = id >> 7, k = id & 127;
    hi[id] = f2bf_rne(W[k * FOUT + n]);
}

__global__ __launch_bounds__(256) void fill_conv_k(
    const int* __restrict__ src, const int* __restrict__ dst,
    const float* __restrict__ dinv, int* __restrict__ rowptr,
    int2* __restrict__ pairs, int E, int fillBlocks,
    const float* __restrict__ W1, const float* __restrict__ W2,
    const float* __restrict__ W3,
    unsigned short* __restrict__ W1h, unsigned short* __restrict__ W2h,
    unsigned short* __restrict__ W3h) {
    if ((int)blockIdx.x < fillBlocks) {
        int e = blockIdx.x * 256 + threadIdx.x;
        if (e < E) {
            int s = src[e], d = dst[e];
            float nrm = dinv[s] * dinv[d];
            int pos = atomicAdd(&rowptr[d], 1);
            pairs[pos] = make_int2(s, __float_as_int(nrm));
        }
    } else {
        int id = (blockIdx.x - fillBlocks) * 256 + threadIdx.x;
        if (id < 16384) convw_one(W1, W1h, 128, id);
        else if (id < 32768) convw_one(W2, W2h, 128, id - 16384);
        else if (id < 40960) convw_one(W3, W3h, 64, id - 32768);
    }
}

// ---------------- MFMA GEMM: T[N][FOUT] = A[N][128] @ W[128][FOUT] ----------
// C = (Ah+Al)*Bh, fp32 acc (B-residual dropped). Output bf16 hi/lo.
// Wave = 32 rows x FOUT cols; block = 4 waves = 128 rows. 16x16x32 layouts
// (m89): A[m=lane&15][k=quad*8+j], B = Wt[n=lane&15][k], C: col=lane&15,
// row=quad*4+reg.
__device__ inline void split8(const float* __restrict__ p, bf16x8& hi, bf16x8& lo) {
    float4 v0 = *(const float4*)p;
    float4 v1 = *(const float4*)(p + 4);
    float vv[8] = {v0.x, v0.y, v0.z, v0.w, v1.x, v1.y, v1.z, v1.w};
#pragma unroll
    for (int i = 0; i < 8; ++i) {
        unsigned short h = f2bf_rne(vv[i]);
        hi[i] = (short)h;
        lo[i] = (short)f2bf_rne(vv[i] - bf2f(h));
    }
}

template <int FOUT, bool AF32>
__global__ __launch_bounds__(256) void mfma_gemm(const float* __restrict__ Af,
                                                 const unsigned short* __restrict__ Ahi,
                                                 const unsigned short* __restrict__ Alo,
                                                 const unsigned short* __restrict__ Bhi,
                                                 unsigned short* __restrict__ Thi,
                                                 unsigned short* __restrict__ Tlo,
                                                 int N) {
    constexpr int NCT = FOUT / 16;
    const int tid = threadIdx.x;
    const int wv = tid >> 6, lane = tid & 63;
    const int quad = lane >> 4, l16 = lane & 15;
    const int row0 = blockIdx.x * 128 + wv * 32;

    f32x4 acc[2][NCT];
#pragma unroll
    for (int rt = 0; rt < 2; ++rt)
#pragma unroll
        for (int ct = 0; ct < NCT; ++ct)
            acc[rt][ct] = (f32x4){0.f, 0.f, 0.f, 0.f};

    const int ra = AF32 ? min(row0 + l16, N - 1) : (row0 + l16);
    const int rb = AF32 ? min(row0 + 16 + l16, N - 1) : (row0 + 16 + l16);

#pragma unroll
    for (int ks = 0; ks < 4; ++ks) {
        const int ko = ks * 32 + quad * 8;
        bf16x8 ah0, ah1, al0, al1;
        if (AF32) {
            split8(Af + (size_t)ra * 128 + ko, ah0, al0);
            split8(Af + (size_t)rb * 128 + ko, ah1, al1);
        } else {
            ah0 = *(const bf16x8*)(Ahi + (size_t)ra * 128 + ko);
            ah1 = *(const bf16x8*)(Ahi + (size_t)rb * 128 + ko);
            al0 = *(const bf16x8*)(Alo + (size_t)ra * 128 + ko);
            al1 = *(const bf16x8*)(Alo + (size_t)rb * 128 + ko);
        }
#pragma unroll
        for (int ct = 0; ct < NCT; ++ct) {
            bf16x8 bh = *(const bf16x8*)(Bhi + (size_t)(ct * 16 + l16) * 128 + ko);
            acc[0][ct] = __builtin_amdgcn_mfma_f32_16x16x32_bf16(ah0, bh, acc[0][ct], 0, 0, 0);
            acc[0][ct] = __builtin_amdgcn_mfma_f32_16x16x32_bf16(al0, bh, acc[0][ct], 0, 0, 0);
            acc[1][ct] = __builtin_amdgcn_mfma_f32_16x16x32_bf16(ah1, bh, acc[1][ct], 0, 0, 0);
            acc[1][ct] = __builtin_amdgcn_mfma_f32_16x16x32_bf16(al1, bh, acc[1][ct], 0, 0, 0);
        }
    }

#pragma unroll
    for (int rt = 0; rt < 2; ++rt) {
        const int rbase = row0 + rt * 16 + quad * 4;
#pragma unroll
        for (int ct = 0; ct < NCT; ++ct) {
            const int col = ct * 16 + l16;
            f32x4 v = acc[rt][ct];
#pragma unroll
            for (int r = 0; r < 4; ++r) {
                if (rbase + r < N) {
                    size_t idx = (size_t)(rbase + r) * FOUT + col;
                    unsigned short h = f2bf_rne(v[r]);
                    Thi[idx] = h;
                    Tlo[idx] = f2bf_rne(v[r] - bf2f(h));
                }
            }
        }
    }
}

// ---------------- aggregation: wave per row, no atomics, no shfl ----------
// res[row] = b + (Thi+Tlo)[row]*dinv^2 + sum_e norm_e * Thi[src_e]
template <int FOUT, bool SPLIT>
__global__ __launch_bounds__(256) void gather_k(const int* __restrict__ rowend,
                                                const int2* __restrict__ pairs,
                                                const float* __restrict__ dinv,
                                                const unsigned short* __restrict__ Thi,
                                                const unsigned short* __restrict__ Tlo,
                                                const float* __restrict__ bias,
                                                float* __restrict__ out,
                                                unsigned short* __restrict__ outHi,
                                                unsigned short* __restrict__ outLo,
                                                int N) {
    const int wave = threadIdx.x >> 6;
    const int lane = threadIdx.x & 63;
    const int row = blockIdx.x * 4 + wave;
    if (row >= N) return;

    const int start = (row == 0) ? 0 : rowend[row - 1];
    const int end = rowend[row];
    const float dr = dinv[row];

    if (FOUT == 128) {
        const unsigned* thi32 = (const unsigned*)Thi;  // bf16x2 per dword
        const unsigned* tlo32 = (const unsigned*)Tlo;
        unsigned sh = thi32[(size_t)row * 64 + lane];
        unsigned sl = tlo32[(size_t)row * 64 + lane];
        float2 bb = *(const float2*)(bias + lane * 2);
        float ax = bb.x + (bf2f_lo(sh) + bf2f_lo(sl)) * dr * dr;
        float ay = bb.y + (bf2f_hi(sh) + bf2f_hi(sl)) * dr * dr;

        int j = start;
        if ((j & 1) && j < end) {
            int2 pv = pairs[j];
            unsigned m = thi32[(size_t)pv.x * 64 + lane];
            float n = __int_as_float(pv.y);
            ax += n * bf2f_lo(m);
            ay += n * bf2f_hi(m);
            ++j;
        }
        for (; j + 4 <= end; j += 4) {
            int4 p01 = *(const int4*)(pairs + j);
            int4 p23 = *(const int4*)(pairs + j + 2);
            unsigned m0 = thi32[(size_t)p01.x * 64 + lane];
            unsigned m1 = thi32[(size_t)p01.z * 64 + lane];
            unsigned m2 = thi32[(size_t)p23.x * 64 + lane];
            unsigned m3 = thi32[(size_t)p23.z * 64 + lane];
            float n0 = __int_as_float(p01.y), n1 = __int_as_float(p01.w);
            float n2 = __int_as_float(p23.y), n3 = __int_as_float(p23.w);
            ax += n0 * bf2f_lo(m0); ay += n0 * bf2f_hi(m0);
            ax += n1 * bf2f_lo(m1); ay += n1 * bf2f_hi(m1);
            ax += n2 * bf2f_lo(m2); ay += n2 * bf2f_hi(m2);
            ax += n3 * bf2f_lo(m3); ay += n3 * bf2f_hi(m3);
        }
        for (; j < end; ++j) {
            int2 pv = pairs[j];
            unsigned m = thi32[(size_t)pv.x * 64 + lane];
            float n = __int_as_float(pv.y);
            ax += n * bf2f_lo(m);
            ay += n * bf2f_hi(m);
        }

        if (SPLIT) {
            float vx = fmaxf(ax, 0.f), vy = fmaxf(ay, 0.f);
            ushort2 h, l;
            h.x = f2bf_rne(vx); l.x = f2bf_rne(vx - bf2f(h.x));
            h.y = f2bf_rne(vy); l.y = f2bf_rne(vy - bf2f(h.y));
            *(ushort2*)(outHi + (size_t)row * 128 + lane * 2) = h;
            *(ushort2*)(outLo + (size_t)row * 128 + lane * 2) = l;
        } else {
            float2 o; o.x = ax; o.y = ay;
            *(float2*)(out + (size_t)row * 128 + lane * 2) = o;
        }
    } else {
        float self = bf2f(Thi[(size_t)row * FOUT + lane]) + bf2f(Tlo[(size_t)row * FOUT + lane]);
        float acc = bias[lane] + self * dr * dr;

        int j = start;
        if ((j & 1) && j < end) {
            int2 pv = pairs[j];
            acc += __int_as_float(pv.y) * bf2f(Thi[(size_t)pv.x * FOUT + lane]);
            ++j;
        }
        for (; j + 4 <= end; j += 4) {
            int4 p01 = *(const int4*)(pairs + j);
            int4 p23 = *(const int4*)(pairs + j + 2);
            float m0 = bf2f(Thi[(size_t)p01.x * FOUT + lane]);
            float m1 = bf2f(Thi[(size_t)p01.z * FOUT + lane]);
            float m2 = bf2f(Thi[(size_t)p23.x * FOUT + lane]);
            float m3 = bf2f(Thi[(size_t)p23.z * FOUT + lane]);
            acc += __int_as_float(p01.y) * m0 + __int_as_float(p01.w) * m1 +
                   __int_as_float(p23.y) * m2 + __int_as_float(p23.w) * m3;
        }
        for (; j < end; ++j) {
            int2 pv = pairs[j];
            acc += __int_as_float(pv.y) * bf2f(Thi[(size_t)pv.x * FOUT + lane]);
        }
        out[(size_t)row * FOUT + lane] = acc;
    }
}

extern "C" void kernel_launch(void* const* d_in, const int* in_sizes, int n_in,
                              void* d_out, int out_size, void* d_ws, size_t ws_size,
                              hipStream_t stream) {
    const float* x  = (const float*)d_in[0];
    const int* eidx = (const int*)d_in[1];
    const float* W1 = (const float*)d_in[2];
    const float* b1 = (const float*)d_in[3];
    const float* W2 = (const float*)d_in[4];
    const float* b2 = (const float*)d_in[5];
    const float* W3 = (const float*)d_in[6];
    const float* b3 = (const float*)d_in[7];
    float* out = (float*)d_out;

    const int N = in_sizes[0] / IN_CH;
    const int E = in_sizes[1] / 2;
    const int* src = eidx;
    const int* dst = eidx + E;
    const int Npad = ((N + 127) / 128) * 128;
    const int nb = (N + 255) / 256;

    auto align = [](size_t v) { return (v + 255) / 256 * 256; };
    char* p = (char*)d_ws;
    int* cnt = (int*)p;            p += align((size_t)N * 4);
    int* rowptr = (int*)p;         p += align((size_t)N * 4);
    int* bsum = (int*)p;           p += align((size_t)nb * 4);
    float* dinv = (float*)p;       p += align((size_t)N * 4);
    int2* pairs = (int2*)p;        p += align((size_t)E * 8);
    unsigned short* Ahi = (unsigned short*)p;  p += align((size_t)Npad * 128 * 2);
    unsigned short* Alo = (unsigned short*)p;  p += align((size_t)Npad * 128 * 2);
    unsigned short* Thi = (unsigned short*)p;  p += align((size_t)Npad * 128 * 2);
    unsigned short* Tlo = (unsigned short*)p;  p += align((size_t)Npad * 128 * 2);
    unsigned short* W1h = (unsigned short*)p;  p += align(128 * 128 * 2);
    unsigned short* W2h = (unsigned short*)p;  p += align(128 * 128 * 2);
    unsigned short* W3h = (unsigned short*)p;

    // ---- CSR build (once; reused by all 3 layers) ----
    hipMemsetAsync(cnt, 0, (size_t)N * 4, stream);
    cnt_k<<<(E + 255) / 256, 256, 0, stream>>>(dst, cnt, E);
    scan1_k<<<nb, 256, 0, stream>>>(cnt, bsum, dinv, N);
    scan2_k<<<1, 512, 0, stream>>>(bsum, nb);
    scan3_k<<<nb, 256, 0, stream>>>(cnt, bsum, rowptr, N);
    const int fillBlocks = (E + 255) / 256;
    fill_conv_k<<<fillBlocks + 160, 256, 0, stream>>>(src, dst, dinv, rowptr, pairs,
                                                      E, fillBlocks, W1, W2, W3,
                                                      W1h, W2h, W3h);
    // rowptr[i] now holds END of row i.

    const int gemm_blocks = (N + 127) / 128;  // 128 rows per block (4 waves x 32)
    const int gather_blocks = (N + 3) / 4;

    // Layer 1 (A = x fp32, split in-register)
    mfma_gemm<128, true><<<gemm_blocks, 256, 0, stream>>>(x, nullptr, nullptr,
                                                          W1h, Thi, Tlo, N);
    gather_k<128, true><<<gather_blocks, 256, 0, stream>>>(rowptr, pairs, dinv, Thi, Tlo,
                                                           b1, nullptr, Ahi, Alo, N);
    // Layer 2
    mfma_gemm<128, false><<<gemm_blocks, 256, 0, stream>>>(nullptr, Ahi, Alo,
                                                           W2h, Thi, Tlo, N);
    gather_k<128, true><<<gather_blocks, 256, 0, stream>>>(rowptr, pairs, dinv, Thi, Tlo,
                                                           b2, nullptr, Ahi, Alo, N);
    // Layer 3
    mfma_gemm<64, false><<<gemm_blocks, 256, 0, stream>>>(nullptr, Ahi, Alo,
                                                          W3h, Thi, Tlo, N);
    gather_k<64, false><<<gather_blocks, 256, 0, stream>>>(rowptr, pairs, dinv, Thi, Tlo,
                                                           b3, out, nullptr, nullptr, N);
}

// Round 8
// 393.346 us; speedup vs baseline: 1.2906x; 1.0835x over previous
//
#include <hip/hip_runtime.h>

// GCN 3-layer forward on gfx950.
// Round 8: GEMM K-loop de-latencied. Bh staged in LDS once per block (shared
// by 4 waves; ds_read ~12cyc vs global ~200cyc chain), 16 rows/wave / 64-row
// blocks (1563 blocks -> ~16 waves/CU vs 12.2). LDS B stride 136 bf16 = 16B
// aligned, lanes 4 banks apart -> 2-way alias only (free, m136).
// R6 lesson: 16-row waves regress IFF B is refetched per-wave from L2.

#define IN_CH 128

typedef __attribute__((ext_vector_type(8))) short bf16x8;
typedef __attribute__((ext_vector_type(4))) float f32x4;

__device__ inline unsigned short f2bf_rne(float f) {
    unsigned u = __float_as_uint(f);
    unsigned r = (u + 0x7FFFu + ((u >> 16) & 1u)) >> 16;
    return (unsigned short)r;
}
__device__ inline float bf2f(unsigned short h) {
    return __uint_as_float(((unsigned)h) << 16);
}
__device__ inline float bf2f_lo(unsigned m) {
    return __uint_as_float(m << 16);
}
__device__ inline float bf2f_hi(unsigned m) {
    return __uint_as_float(m & 0xffff0000u);
}

// ---------------- degree count ----------------
__global__ __launch_bounds__(256) void cnt_k(const int* __restrict__ dst,
                                             int* __restrict__ cnt, int E) {
    int e = blockIdx.x * 256 + threadIdx.x;
    if (e < E) atomicAdd(&cnt[dst[e]], 1);
}

// ---------------- scan stage 1 (+ dinv fused) ----------------
__global__ __launch_bounds__(256) void scan1_k(const int* __restrict__ cnt,
                                               int* __restrict__ bsum,
                                               float* __restrict__ dinv, int N) {
    __shared__ int s[256];
    int tid = threadIdx.x;
    int i = blockIdx.x * 256 + tid;
    int v = (i < N) ? cnt[i] : 0;
    if (i < N) dinv[i] = rsqrtf((float)v + 1.0f);
    s[tid] = v;
    __syncthreads();
    for (int off = 128; off > 0; off >>= 1) {
        if (tid < off) s[tid] += s[tid + off];
        __syncthreads();
    }
    if (tid == 0) bsum[blockIdx.x] = s[0];
}

__global__ __launch_bounds__(512) void scan2_k(int* __restrict__ bsum, int nb) {
    __shared__ int s[512];
    __shared__ int carry_s;
    int tid = threadIdx.x;
    if (tid == 0) carry_s = 0;
    __syncthreads();
    for (int base = 0; base < nb; base += 512) {
        int c = carry_s;
        int i = base + tid;
        int v = (i < nb) ? bsum[i] : 0;
        s[tid] = v;
        __syncthreads();
        for (int off = 1; off < 512; off <<= 1) {
            int t = (tid >= off) ? s[tid - off] : 0;
            __syncthreads();
            s[tid] += t;
            __syncthreads();
        }
        if (i < nb) bsum[i] = s[tid] - v + c;
        __syncthreads();
        if (tid == 0) carry_s = c + s[511];
        __syncthreads();
    }
}

__global__ __launch_bounds__(256) void scan3_k(const int* __restrict__ cnt,
                                               const int* __restrict__ bsum,
                                               int* __restrict__ rowptr, int N) {
    __shared__ int s[256];
    int tid = threadIdx.x;
    int i = blockIdx.x * 256 + tid;
    int v = (i < N) ? cnt[i] : 0;
    s[tid] = v;
    __syncthreads();
    for (int off = 1; off < 256; off <<= 1) {
        int t = (tid >= off) ? s[tid - off] : 0;
        __syncthreads();
        s[tid] += t;
        __syncthreads();
    }
    if (i < N) rowptr[i] = s[tid] - v + bsum[blockIdx.x];
}

// ---------------- fill (CSR pairs) + weight conversion, one launch ----------
__device__ inline void convw_one(const float* W, unsigned short* hi, int FOUT, int id) {
    int n = id >> 7, k = id & 127;
    hi[id] = f2bf_rne(W[k * FOUT + n]);
}

__global__ __launch_bounds__(256) void fill_conv_k(
    const int* __restrict__ src, const int* __restrict__ dst,
    const float* __restrict__ dinv, int* __restrict__ rowptr,
    int2* __restrict__ pairs, int E, int fillBlocks,
    const float* __restrict__ W1, const float* __restrict__ W2,
    const float* __restrict__ W3,
    unsigned short* __restrict__ W1h, unsigned short* __restrict__ W2h,
    unsigned short* __restrict__ W3h) {
    if ((int)blockIdx.x < fillBlocks) {
        int e = blockIdx.x * 256 + threadIdx.x;
        if (e < E) {
            int s = src[e], d = dst[e];
            float nrm = dinv[s] * dinv[d];
            int pos = atomicAdd(&rowptr[d], 1);
            pairs[pos] = make_int2(s, __float_as_int(nrm));
        }
    } else {
        int id = (blockIdx.x - fillBlocks) * 256 + threadIdx.x;
        if (id < 16384) convw_one(W1, W1h, 128, id);
        else if (id < 32768) convw_one(W2, W2h, 128, id - 16384);
        else if (id < 40960) convw_one(W3, W3h, 64, id - 32768);
    }
}

// ---------------- MFMA GEMM: T[N][FOUT] = A[N][128] @ W[128][FOUT] ----------
// C = (Ah+Al)*Bh, fp32 acc. Output bf16 hi/lo. Block = 4 waves x 16 rows =
// 64 rows. Bh (Wt[FOUT][128]) staged in LDS once per block, padded stride 136.
// 16x16x32 layouts (m89): A[m=lane&15][k=quad*8+j], B = Wt[n=lane&15][k],
// C: col=lane&15, row=quad*4+reg.
__device__ inline void split8(const float* __restrict__ p, bf16x8& hi, bf16x8& lo) {
    float4 v0 = *(const float4*)p;
    float4 v1 = *(const float4*)(p + 4);
    float vv[8] = {v0.x, v0.y, v0.z, v0.w, v1.x, v1.y, v1.z, v1.w};
#pragma unroll
    for (int i = 0; i < 8; ++i) {
        unsigned short h = f2bf_rne(vv[i]);
        hi[i] = (short)h;
        lo[i] = (short)f2bf_rne(vv[i] - bf2f(h));
    }
}

template <int FOUT, bool AF32>
__global__ __launch_bounds__(256) void mfma_gemm(const float* __restrict__ Af,
                                                 const unsigned short* __restrict__ Ahi,
                                                 const unsigned short* __restrict__ Alo,
                                                 const unsigned short* __restrict__ Bhi,
                                                 unsigned short* __restrict__ Thi,
                                                 unsigned short* __restrict__ Tlo,
                                                 int N) {
    constexpr int NCT = FOUT / 16;
    constexpr int BSTRIDE = 136;  // bf16 units; 272B row = 16B aligned, 2-way bank alias
    __shared__ unsigned short Bs[FOUT * BSTRIDE];

    const int tid = threadIdx.x;
    const int wv = tid >> 6, lane = tid & 63;
    const int quad = lane >> 4, l16 = lane & 15;
    const int row0 = blockIdx.x * 64 + wv * 16;  // 16 rows per wave

    // ---- stage Bh into LDS (once per block) ----
    // FOUT rows x 128 bf16; 16B chunks: FOUT*16 chunks over 256 threads.
#pragma unroll
    for (int it = 0; it < FOUT / 16; ++it) {
        int i = it * 256 + tid;          // chunk index
        int r = i >> 4, c = (i & 15) * 8;  // row, bf16 offset
        *(bf16x8*)(&Bs[r * BSTRIDE + c]) = *(const bf16x8*)(Bhi + (size_t)r * 128 + c);
    }
    __syncthreads();

    f32x4 acc[NCT];
#pragma unroll
    for (int ct = 0; ct < NCT; ++ct)
        acc[ct] = (f32x4){0.f, 0.f, 0.f, 0.f};

    const int ra = AF32 ? min(row0 + l16, N - 1) : (row0 + l16);

#pragma unroll
    for (int ks = 0; ks < 4; ++ks) {
        const int ko = ks * 32 + quad * 8;
        bf16x8 ah, al;
        if (AF32) {
            split8(Af + (size_t)ra * 128 + ko, ah, al);
        } else {
            ah = *(const bf16x8*)(Ahi + (size_t)ra * 128 + ko);
            al = *(const bf16x8*)(Alo + (size_t)ra * 128 + ko);
        }
#pragma unroll
        for (int ct = 0; ct < NCT; ++ct) {
            bf16x8 bh = *(const bf16x8*)(&Bs[(ct * 16 + l16) * BSTRIDE + ko]);
            acc[ct] = __builtin_amdgcn_mfma_f32_16x16x32_bf16(ah, bh, acc[ct], 0, 0, 0);
            acc[ct] = __builtin_amdgcn_mfma_f32_16x16x32_bf16(al, bh, acc[ct], 0, 0, 0);
        }
    }

    const int rbase = row0 + quad * 4;
#pragma unroll
    for (int ct = 0; ct < NCT; ++ct) {
        const int col = ct * 16 + l16;
        f32x4 v = acc[ct];
#pragma unroll
        for (int r = 0; r < 4; ++r) {
            if (rbase + r < N) {
                size_t idx = (size_t)(rbase + r) * FOUT + col;
                unsigned short h = f2bf_rne(v[r]);
                Thi[idx] = h;
                Tlo[idx] = f2bf_rne(v[r] - bf2f(h));
            }
        }
    }
}

// ---------------- aggregation: wave per row, no atomics, no shfl ----------
// res[row] = b + (Thi+Tlo)[row]*dinv^2 + sum_e norm_e * Thi[src_e]
template <int FOUT, bool SPLIT>
__global__ __launch_bounds__(256) void gather_k(const int* __restrict__ rowend,
                                                const int2* __restrict__ pairs,
                                                const float* __restrict__ dinv,
                                                const unsigned short* __restrict__ Thi,
                                                const unsigned short* __restrict__ Tlo,
                                                const float* __restrict__ bias,
                                                float* __restrict__ out,
                                                unsigned short* __restrict__ outHi,
                                                unsigned short* __restrict__ outLo,
                                                int N) {
    const int wave = threadIdx.x >> 6;
    const int lane = threadIdx.x & 63;
    const int row = blockIdx.x * 4 + wave;
    if (row >= N) return;

    const int start = (row == 0) ? 0 : rowend[row - 1];
    const int end = rowend[row];
    const float dr = dinv[row];

    if (FOUT == 128) {
        const unsigned* thi32 = (const unsigned*)Thi;  // bf16x2 per dword
        const unsigned* tlo32 = (const unsigned*)Tlo;
        unsigned sh = thi32[(size_t)row * 64 + lane];
        unsigned sl = tlo32[(size_t)row * 64 + lane];
        float2 bb = *(const float2*)(bias + lane * 2);
        float ax = bb.x + (bf2f_lo(sh) + bf2f_lo(sl)) * dr * dr;
        float ay = bb.y + (bf2f_hi(sh) + bf2f_hi(sl)) * dr * dr;

        int j = start;
        if ((j & 1) && j < end) {
            int2 pv = pairs[j];
            unsigned m = thi32[(size_t)pv.x * 64 + lane];
            float n = __int_as_float(pv.y);
            ax += n * bf2f_lo(m);
            ay += n * bf2f_hi(m);
            ++j;
        }
        for (; j + 4 <= end; j += 4) {
            int4 p01 = *(const int4*)(pairs + j);
            int4 p23 = *(const int4*)(pairs + j + 2);
            unsigned m0 = thi32[(size_t)p01.x * 64 + lane];
            unsigned m1 = thi32[(size_t)p01.z * 64 + lane];
            unsigned m2 = thi32[(size_t)p23.x * 64 + lane];
            unsigned m3 = thi32[(size_t)p23.z * 64 + lane];
            float n0 = __int_as_float(p01.y), n1 = __int_as_float(p01.w);
            float n2 = __int_as_float(p23.y), n3 = __int_as_float(p23.w);
            ax += n0 * bf2f_lo(m0); ay += n0 * bf2f_hi(m0);
            ax += n1 * bf2f_lo(m1); ay += n1 * bf2f_hi(m1);
            ax += n2 * bf2f_lo(m2); ay += n2 * bf2f_hi(m2);
            ax += n3 * bf2f_lo(m3); ay += n3 * bf2f_hi(m3);
        }
        for (; j < end; ++j) {
            int2 pv = pairs[j];
            unsigned m = thi32[(size_t)pv.x * 64 + lane];
            float n = __int_as_float(pv.y);
            ax += n * bf2f_lo(m);
            ay += n * bf2f_hi(m);
        }

        if (SPLIT) {
            float vx = fmaxf(ax, 0.f), vy = fmaxf(ay, 0.f);
            ushort2 h, l;
            h.x = f2bf_rne(vx); l.x = f2bf_rne(vx - bf2f(h.x));
            h.y = f2bf_rne(vy); l.y = f2bf_rne(vy - bf2f(h.y));
            *(ushort2*)(outHi + (size_t)row * 128 + lane * 2) = h;
            *(ushort2*)(outLo + (size_t)row * 128 + lane * 2) = l;
        } else {
            float2 o; o.x = ax; o.y = ay;
            *(float2*)(out + (size_t)row * 128 + lane * 2) = o;
        }
    } else {
        float self = bf2f(Thi[(size_t)row * FOUT + lane]) + bf2f(Tlo[(size_t)row * FOUT + lane]);
        float acc = bias[lane] + self * dr * dr;

        int j = start;
        if ((j & 1) && j < end) {
            int2 pv = pairs[j];
            acc += __int_as_float(pv.y) * bf2f(Thi[(size_t)pv.x * FOUT + lane]);
            ++j;
        }
        for (; j + 4 <= end; j += 4) {
            int4 p01 = *(const int4*)(pairs + j);
            int4 p23 = *(const int4*)(pairs + j + 2);
            float m0 = bf2f(Thi[(size_t)p01.x * FOUT + lane]);
            float m1 = bf2f(Thi[(size_t)p01.z * FOUT + lane]);
            float m2 = bf2f(Thi[(size_t)p23.x * FOUT + lane]);
            float m3 = bf2f(Thi[(size_t)p23.z * FOUT + lane]);
            acc += __int_as_float(p01.y) * m0 + __int_as_float(p01.w) * m1 +
                   __int_as_float(p23.y) * m2 + __int_as_float(p23.w) * m3;
        }
        for (; j < end; ++j) {
            int2 pv = pairs[j];
            acc += __int_as_float(pv.y) * bf2f(Thi[(size_t)pv.x * FOUT + lane]);
        }
        out[(size_t)row * FOUT + lane] = acc;
    }
}

extern "C" void kernel_launch(void* const* d_in, const int* in_sizes, int n_in,
                              void* d_out, int out_size, void* d_ws, size_t ws_size,
                              hipStream_t stream) {
    const float* x  = (const float*)d_in[0];
    const int* eidx = (const int*)d_in[1];
    const float* W1 = (const float*)d_in[2];
    const float* b1 = (const float*)d_in[3];
    const float* W2 = (const float*)d_in[4];
    const float* b2 = (const float*)d_in[5];
    const float* W3 = (const float*)d_in[6];
    const float* b3 = (const float*)d_in[7];
    float* out = (float*)d_out;

    const int N = in_sizes[0] / IN_CH;
    const int E = in_sizes[1] / 2;
    const int* src = eidx;
    const int* dst = eidx + E;
    const int Npad = ((N + 127) / 128) * 128;
    const int nb = (N + 255) / 256;

    auto align = [](size_t v) { return (v + 255) / 256 * 256; };
    char* p = (char*)d_ws;
    int* cnt = (int*)p;            p += align((size_t)N * 4);
    int* rowptr = (int*)p;         p += align((size_t)N * 4);
    int* bsum = (int*)p;           p += align((size_t)nb * 4);
    float* dinv = (float*)p;       p += align((size_t)N * 4);
    int2* pairs = (int2*)p;        p += align((size_t)E * 8);
    unsigned short* Ahi = (unsigned short*)p;  p += align((size_t)Npad * 128 * 2);
    unsigned short* Alo = (unsigned short*)p;  p += align((size_t)Npad * 128 * 2);
    unsigned short* Thi = (unsigned short*)p;  p += align((size_t)Npad * 128 * 2);
    unsigned short* Tlo = (unsigned short*)p;  p += align((size_t)Npad * 128 * 2);
    unsigned short* W1h = (unsigned short*)p;  p += align(128 * 128 * 2);
    unsigned short* W2h = (unsigned short*)p;  p += align(128 * 128 * 2);
    unsigned short* W3h = (unsigned short*)p;

    // ---- CSR build (once; reused by all 3 layers) ----
    hipMemsetAsync(cnt, 0, (size_t)N * 4, stream);
    cnt_k<<<(E + 255) / 256, 256, 0, stream>>>(dst, cnt, E);
    scan1_k<<<nb, 256, 0, stream>>>(cnt, bsum, dinv, N);
    scan2_k<<<1, 512, 0, stream>>>(bsum, nb);
    scan3_k<<<nb, 256, 0, stream>>>(cnt, bsum, rowptr, N);
    const int fillBlocks = (E + 255) / 256;
    fill_conv_k<<<fillBlocks + 160, 256, 0, stream>>>(src, dst, dinv, rowptr, pairs,
                                                      E, fillBlocks, W1, W2, W3,
                                                      W1h, W2h, W3h);
    // rowptr[i] now holds END of row i.

    const int gemm_blocks = (N + 63) / 64;  // 64 rows per block (4 waves x 16)
    const int gather_blocks = (N + 3) / 4;

    // Layer 1 (A = x fp32, split in-register)
    mfma_gemm<128, true><<<gemm_blocks, 256, 0, stream>>>(x, nullptr, nullptr,
                                                          W1h, Thi, Tlo, N);
    gather_k<128, true><<<gather_blocks, 256, 0, stream>>>(rowptr, pairs, dinv, Thi, Tlo,
                                                           b1, nullptr, Ahi, Alo, N);
    // Layer 2
    mfma_gemm<128, false><<<gemm_blocks, 256, 0, stream>>>(nullptr, Ahi, Alo,
                                                           W2h, Thi, Tlo, N);
    gather_k<128, true><<<gather_blocks, 256, 0, stream>>>(rowptr, pairs, dinv, Thi, Tlo,
                                                           b2, nullptr, Ahi, Alo, N);
    // Layer 3
    mfma_gemm<64, false><<<gemm_blocks, 256, 0, stream>>>(nullptr, Ahi, Alo,
                                                          W3h, Thi, Tlo, N);
    gather_k<64, false><<<gather_blocks, 256, 0, stream>>>(rowptr, pairs, dinv, Thi, Tlo,
                                                           b3, out, nullptr, nullptr, N);
}